// Round 3
// baseline (306.372 us; speedup 1.0000x reference)
//
#include <hip/hip_runtime.h>
#include <hip/hip_bf16.h>

#define BATCH 32
#define WDIM 512
#define HDIM 512
#define CDIM 3
#define KPSF 32
#define NPRED (BATCH*WDIM*HDIM*CDIM)  // 25165824

#define TW 88        // tile width  (x): 64 + 15 + 9 pad -> 8-elem aligned rows
#define TH 63        // tile height (y): 32 + 31
#define TE (TW*TH)   // 5544 per channel
#define TALL (TW*TH*CDIM)  // 16632 dense elements

typedef __bf16 bf16x8 __attribute__((ext_vector_type(8)));
typedef float floatx16 __attribute__((ext_vector_type(16)));

// Pack psf[b,i,j,0,c] (fp32) into MFMA A-fragment order (bf16):
// dst[((c*32 + j)*2 + h)*64 + lane][t] = psf[b=lane&31][i=16h+8*(lane>>5)+t][j][c]
__global__ __launch_bounds__(64) void pack_psf(const float* __restrict__ psf,
                                               __bf16* __restrict__ dst,
                                               float* __restrict__ loss) {
    if (blockIdx.x == 0 && threadIdx.x == 0) *loss = 0.f;
    int idx = blockIdx.x;              // [0,192) = ((c*32 + j)*2 + h)
    int h = idx & 1;
    int j = (idx >> 1) & 31;
    int c = idx >> 6;
    int lane = threadIdx.x;
    int b = lane & 31;
    int q = lane >> 5;
    bf16x8 v;
#pragma unroll
    for (int t = 0; t < 8; ++t) {
        int i = 16*h + 8*q + t;
        v[t] = (__bf16)psf[((size_t)(b*KPSF + i)*KPSF + j)*CDIM + c];
    }
    *(bf16x8*)(dst + (size_t)(idx*64 + lane)*8) = v;
}

// Block = 384 threads = 6 waves. Wave w: channel c = w>>1, s-half sh = w&1.
// Wave covers x's = x0 + 8*(sh*4 + ss), ss=0..3. MFMA m=batch, n=y, k=i-taps.
__global__ __launch_bounds__(384, 3) void conv_mfma(
    const float* __restrict__ obs,    // [B,W,H,C]
    const float* __restrict__ img,    // [W,H,C]
    const __bf16* __restrict__ psfA,  // packed A-frags
    float* __restrict__ out)          // [B,W,H,C] pred, then loss scalar
{
    // sImg (main loop) and sOut (epilogue staging) share the same LDS.
    __shared__ __align__(16) unsigned char smem[CDIM*TE*2];  // 33264 B
    __bf16 (*sImg)[TE] = (__bf16 (*)[TE])smem;
    float* sOut = (float*)smem;                               // 16384 B used

    const int tid  = threadIdx.x;
    const int lane = tid & 63;
    const int w    = tid >> 6;      // wave 0..5
    const int c    = w >> 1;        // channel
    const int sh   = w & 1;         // s-half
    const int n    = lane & 31;     // MFMA n (y within tile)
    const int q    = lane >> 5;     // k-half selector

    const int bx = blockIdx.x;      // [0,1024)
    const int r  = bx & 7;          // x mod-8 class
    const int g  = (bx >> 3) & 7;   // 64-wide x group
    const int yt = bx >> 6;         // y tile [0,16)
    const int x0 = g*64 + r;        // block's x's = x0 + 8s, s=0..7
    const int ytile = yt*32;

    // ---- stage transposed image tile, dense/coalesced across (x,y,c) ----
    const bool interior = (x0 >= 15) && (x0 <= WDIM - 73) &&
                          (ytile >= 15) && (ytile <= HDIM - 48);
    if (interior) {
        const float* ibase = img + ((size_t)(x0-15)*HDIM + (ytile-15))*CDIM;
#pragma unroll 4
        for (int e = tid; e < TALL; e += 384) {
            int xl = e / (TH*CDIM);
            int rr = e - xl*(TH*CDIM);
            int yl = rr / 3;
            int cc = rr - yl*3;
            float v = ibase[(size_t)xl*(HDIM*CDIM) + rr];
            sImg[cc][yl*TW + xl] = (__bf16)v;
        }
    } else {
#pragma unroll 4
        for (int e = tid; e < TALL; e += 384) {
            int xl = e / (TH*CDIM);
            int rr = e - xl*(TH*CDIM);
            int yl = rr / 3;
            int cc = rr - yl*3;
            int xg = x0 + xl - 15;
            int yg = ytile + yl - 15;
            float v = 0.f;
            if ((unsigned)xg < WDIM && (unsigned)yg < HDIM)
                v = img[((size_t)xg*HDIM + yg)*CDIM + cc];
            sImg[cc][yl*TW + xl] = (__bf16)v;
        }
    }
    __syncthreads();

    // ---- main loop: LDS reads + MFMA, A(j+1) prefetched from L2 ----
    floatx16 acc[4] = {};
    const __bf16* pA = psfA + (size_t)c*(KPSF*2*64*8) + (size_t)lane*8;
    const __bf16* sI = (const __bf16*)&sImg[c][q*8 + sh*32];  // fold q,sh offsets

    bf16x8 A0 = *(const bf16x8*)(pA);
    bf16x8 A1 = *(const bf16x8*)(pA + 512);
#pragma unroll 4
    for (int j = 0; j < 32; ++j) {
        bf16x8 cA0 = A0, cA1 = A1;
        if (j < 31) {
            A0 = *(const bf16x8*)(pA + (size_t)(j+1)*1024);
            A1 = *(const bf16x8*)(pA + (size_t)(j+1)*1024 + 512);
        }
        const __bf16* rowp = sI + (n + j)*TW;
        bf16x8 C[6];
#pragma unroll
        for (int rr = 0; rr < 6; ++rr)
            C[rr] = *(const bf16x8*)(rowp + rr*8);   // 16B-aligned ds_read_b128
#pragma unroll
        for (int ss = 0; ss < 4; ++ss) {
            acc[ss] = __builtin_amdgcn_mfma_f32_32x32x16_bf16(cA0, C[ss],   acc[ss], 0, 0, 0);
            acc[ss] = __builtin_amdgcn_mfma_f32_32x32x16_bf16(cA1, C[ss+2], acc[ss], 0, 0, 0);
        }
    }

    // ---- epilogue: LDS round-trip -> coalesced float4 + pipelined obs ----
    float ls = 0.f;
    size_t base0, base1;
    {
        int f0 = tid,       fb0 = f0 / 24, rem0 = (f0 - fb0*24) * 4;
        int f1 = tid + 384, fb1 = f1 / 24, rem1 = (f1 - fb1*24) * 4;
        base0 = (((size_t)fb0*WDIM + x0)*HDIM + ytile)*CDIM + rem0;
        base1 = (((size_t)fb1*WDIM + x0)*HDIM + ytile)*CDIM + rem1;
    }
    float4 ob0 = *(const float4*)&obs[base0];
    float4 ob1 = *(const float4*)&obs[base1];

#pragma unroll 1
    for (int s = 0; s < 8; ++s) {
        __syncthreads();   // previous phase's LDS reads complete
        if (sh == (s >> 2)) {
            const int ss = s & 3;
#pragma unroll
            for (int rr = 0; rr < 16; ++rr) {
                int b = (rr & 3) + 8*(rr >> 2) + 4*q;   // D row = batch
                sOut[(b*32 + n)*3 + c] = acc[ss][rr];   // bank 3n+c: conflict-free
            }
        }
        __syncthreads();
        float4 c0 = ob0, c1 = ob1;
        if (s < 7) {       // prefetch next round's obs (overlaps LDS + stores)
            ob0 = *(const float4*)&obs[base0 + (size_t)(s+1)*8*HDIM*CDIM];
            ob1 = *(const float4*)&obs[base1 + (size_t)(s+1)*8*HDIM*CDIM];
        }
        float4 p0 = *(const float4*)&sOut[4*tid];
        float4 p1 = *(const float4*)&sOut[4*(tid + 384)];
        *(float4*)&out[base0 + (size_t)s*8*HDIM*CDIM] = p0;
        *(float4*)&out[base1 + (size_t)s*8*HDIM*CDIM] = p1;
        float d0 = c0.x - p0.x, d1 = c0.y - p0.y, d2 = c0.z - p0.z, d3 = c0.w - p0.w;
        float e0 = c1.x - p1.x, e1 = c1.y - p1.y, e2 = c1.z - p1.z, e3 = c1.w - p1.w;
        ls += d0*d0 + d1*d1 + d2*d2 + d3*d3;
        ls += e0*e0 + e1*e1 + e2*e2 + e3*e3;
    }

#pragma unroll
    for (int m = 32; m >= 1; m >>= 1) ls += __shfl_xor(ls, m, 64);
    if (lane == 0) atomicAdd(out + NPRED, ls * (1.0f/(float)NPRED));
}

extern "C" void kernel_launch(void* const* d_in, const int* in_sizes, int n_in,
                              void* d_out, int out_size, void* d_ws, size_t ws_size,
                              hipStream_t stream) {
    const float* obs = (const float*)d_in[0];   // observed_images [32,512,512,3]
    const float* img = (const float*)d_in[1];   // estimated_image [512,512,3]
    const float* psf = (const float*)d_in[2];   // psfs [32,32,32,1,3]
    float* out = (float*)d_out;                 // pred (25165824) + loss (1)
    __bf16* psfA = (__bf16*)d_ws;               // 196608 B packed psf frags

    pack_psf<<<192, 64, 0, stream>>>(psf, psfA, out + NPRED);
    conv_mfma<<<1024, 384, 0, stream>>>(obs, img, psfA, out);
}

// Round 5
// 263.118 us; speedup vs baseline: 1.1644x; 1.1644x over previous
//
#include <hip/hip_runtime.h>
#include <hip/hip_bf16.h>

#define BATCH 32
#define WDIM 512
#define HDIM 512
#define CDIM 3
#define KPSF 32
#define NPRED (BATCH*WDIM*HDIM*CDIM)  // 25165824

#define TW 88        // tile width  (x): 64 + 15 + 9 pad -> 8-elem aligned rows
#define TH 63        // tile height (y): 32 + 31
#define TE (TW*TH)   // 5544 per channel
#define TALL (TW*TH*CDIM)  // 16632 dense elements

typedef __bf16 bf16x8 __attribute__((ext_vector_type(8)));
typedef float floatx16 __attribute__((ext_vector_type(16)));
typedef float fx4 __attribute__((ext_vector_type(4)));   // clang vector: ok for nontemporal builtins

// Workgroup barrier that does NOT drain vmcnt: only LDS ordering is required
// between epilogue rounds; global loads/stores stay in flight across rounds.
__device__ __forceinline__ void barrier_lgkm() {
    __asm__ volatile("s_waitcnt lgkmcnt(0)\n\ts_barrier" ::: "memory");
}

// Pack psf[b,i,j,0,c] (fp32) into MFMA A-fragment order (bf16):
// dst[((c*32 + j)*2 + h)*64 + lane][t] = psf[b=lane&31][i=16h+8*(lane>>5)+t][j][c]
__global__ __launch_bounds__(64) void pack_psf(const float* __restrict__ psf,
                                               __bf16* __restrict__ dst,
                                               float* __restrict__ loss) {
    if (blockIdx.x == 0 && threadIdx.x == 0) *loss = 0.f;
    int idx = blockIdx.x;              // [0,192) = ((c*32 + j)*2 + h)
    int h = idx & 1;
    int j = (idx >> 1) & 31;
    int c = idx >> 6;
    int lane = threadIdx.x;
    int b = lane & 31;
    int q = lane >> 5;
    bf16x8 v;
#pragma unroll
    for (int t = 0; t < 8; ++t) {
        int i = 16*h + 8*q + t;
        v[t] = (__bf16)psf[((size_t)(b*KPSF + i)*KPSF + j)*CDIM + c];
    }
    *(bf16x8*)(dst + (size_t)(idx*64 + lane)*8) = v;
}

// Block = 192 threads = 3 waves; wave w = channel c of the same
// (x-set of 8 x's at stride 8, y-tile of 32). MFMA m=batch, n=y, k=i-taps.
__global__ __launch_bounds__(192, 2) void conv_mfma(
    const float* __restrict__ obs,    // [B,W,H,C]
    const float* __restrict__ img,    // [W,H,C]
    const __bf16* __restrict__ psfA,  // packed A-frags
    float* __restrict__ out)          // [B,W,H,C] pred, then loss scalar
{
    // sImg (main loop) and sOut (epilogue staging) share the same LDS.
    __shared__ __align__(16) unsigned char smem[CDIM*TE*2];  // 33264 B
    __bf16 (*sImg)[TE] = (__bf16 (*)[TE])smem;
    float* sOut = (float*)smem;                               // 12288 B used

    const int tid  = threadIdx.x;
    const int lane = tid & 63;
    const int c    = tid >> 6;      // wave index = channel
    const int n    = lane & 31;     // MFMA n (y within tile)
    const int q    = lane >> 5;     // k-half selector

    const int bx = blockIdx.x;      // [0,1024)
    const int r8 = bx & 7;          // x mod-8 class
    const int g  = (bx >> 3) & 7;   // 64-wide x group
    const int yt = bx >> 6;         // y tile [0,16)
    const int x0 = g*64 + r8;       // wave's x's = x0 + 8s, s=0..7
    const int ytile = yt*32;

    // ---- stage transposed image tile ----
    const bool interior = (x0 >= 15) && (x0 <= WDIM - 73) &&
                          (ytile >= 15) && (ytile <= HDIM - 48);
    if (interior) {
        // float4 path: per x-row, the 189-float column run starts at a uniform
        // misalignment p2; load alignment-shifted float4 slots and scatter to LDS.
        const int col0 = (ytile - 15)*3;           // >= 0
        const int p2 = col0 & 3;
        const float* gb = img + (size_t)(x0 - 15)*(HDIM*CDIM) + (col0 - p2);
#pragma unroll 2
        for (int f = tid; f < 88*48; f += 192) {
            int r = f / 48;                        // x-row 0..87
            int v = f - r*48;                      // float4 slot 0..47
            fx4 val = *(const fx4*)(gb + (size_t)r*(HDIM*CDIM) + 4*v);
            int d = 4*v - p2;                      // col offset of val[0], in [-3,189)
#pragma unroll
            for (int u = 0; u < 4; ++u) {
                int dd = d + u;
                if (dd >= 0 && dd < 189) {
                    int yl = (dd*171) >> 9;        // dd/3 for dd<511
                    int cc = dd - 3*yl;
                    sImg[cc][yl*TW + r] = (__bf16)val[u];
                }
            }
        }
    } else {
#pragma unroll 4
        for (int e = tid; e < TALL; e += 192) {
            int xl = e / (TH*CDIM);
            int rr = e - xl*(TH*CDIM);
            int yl = rr / 3;
            int cc = rr - yl*3;
            int xg = x0 + xl - 15;
            int yg = ytile + yl - 15;
            float v = 0.f;
            if ((unsigned)xg < WDIM && (unsigned)yg < HDIM)
                v = img[((size_t)xg*HDIM + yg)*CDIM + cc];
            sImg[cc][yl*TW + xl] = (__bf16)v;
        }
    }
    __syncthreads();

    // ---- main loop: LDS reads + MFMA, A(j+1) prefetched from L2 ----
    floatx16 acc[8] = {};
    const __bf16* pA = psfA + (size_t)c*(KPSF*2*64*8) + (size_t)lane*8;
    const __bf16* sI = (const __bf16*)&sImg[c][q*8];

    bf16x8 A0 = *(const bf16x8*)(pA);
    bf16x8 A1 = *(const bf16x8*)(pA + 512);
#pragma unroll 4
    for (int j = 0; j < 32; ++j) {
        bf16x8 cA0 = A0, cA1 = A1;
        if (j < 31) {
            A0 = *(const bf16x8*)(pA + (size_t)(j+1)*1024);
            A1 = *(const bf16x8*)(pA + (size_t)(j+1)*1024 + 512);
        }
        const __bf16* rowp = sI + (n + j)*TW;
        bf16x8 C[10];
#pragma unroll
        for (int rr = 0; rr < 10; ++rr)
            C[rr] = *(const bf16x8*)(rowp + rr*8);   // 16B-aligned ds_read_b128
#pragma unroll
        for (int s = 0; s < 8; ++s) {
            acc[s] = __builtin_amdgcn_mfma_f32_32x32x16_bf16(cA0, C[s],   acc[s], 0, 0, 0);
            acc[s] = __builtin_amdgcn_mfma_f32_32x32x16_bf16(cA1, C[s+2], acc[s], 0, 0, 0);
        }
    }

    // ---- epilogue: LDS transpose rounds with lgkm-only barriers ----
    // obs/out traffic pipelines freely across rounds (no vmcnt drain).
    float ls = 0.f;
    size_t base[4];
#pragma unroll
    for (int k = 0; k < 4; ++k) {
        int f = tid + 192*k;                    // float4 index [0,768)
        int fb = f / 24;                        // batch
        int rem = (f - fb*24) * 4;              // offset in 96-float run
        base[k] = (((size_t)fb*WDIM + x0)*HDIM + ytile)*CDIM + rem;
    }
    fx4 obA[4], obB[4];
#pragma unroll
    for (int k = 0; k < 4; ++k)
        obA[k] = __builtin_nontemporal_load((const fx4*)&obs[base[k]]);
#pragma unroll
    for (int k = 0; k < 4; ++k)
        obB[k] = __builtin_nontemporal_load((const fx4*)&obs[base[k] + 8*HDIM*CDIM]);

#pragma unroll 1
    for (int s = 0; s < 8; ++s) {
        barrier_lgkm();    // previous round's sOut reads complete (LDS only)
#pragma unroll
        for (int rr = 0; rr < 16; ++rr) {
            int b = (rr & 3) + 8*(rr >> 2) + 4*q;   // D row = batch
            sOut[(b*32 + n)*3 + c] = acc[s][rr];    // bank 3n+c: conflict-free
        }
        barrier_lgkm();    // sOut writes visible (LDS only)
        fx4 cur[4];
#pragma unroll
        for (int k = 0; k < 4; ++k) { cur[k] = obA[k]; obA[k] = obB[k]; }
        if (s < 6) {       // depth-2 prefetch: ~2 rounds to cover HBM latency
#pragma unroll
            for (int k = 0; k < 4; ++k)
                obB[k] = __builtin_nontemporal_load(
                    (const fx4*)&obs[base[k] + (size_t)(s+2)*8*HDIM*CDIM]);
        }
#pragma unroll
        for (int k = 0; k < 4; ++k) {
            fx4 p = *(const fx4*)&sOut[4*(tid + 192*k)];
            __builtin_nontemporal_store(p, (fx4*)&out[base[k] + (size_t)s*8*HDIM*CDIM]);
            fx4 d = cur[k] - p;
            ls += d[0]*d[0] + d[1]*d[1] + d[2]*d[2] + d[3]*d[3];
        }
    }

#pragma unroll
    for (int m = 32; m >= 1; m >>= 1) ls += __shfl_xor(ls, m, 64);
    if (lane == 0) atomicAdd(out + NPRED, ls * (1.0f/(float)NPRED));
}

extern "C" void kernel_launch(void* const* d_in, const int* in_sizes, int n_in,
                              void* d_out, int out_size, void* d_ws, size_t ws_size,
                              hipStream_t stream) {
    const float* obs = (const float*)d_in[0];   // observed_images [32,512,512,3]
    const float* img = (const float*)d_in[1];   // estimated_image [512,512,3]
    const float* psf = (const float*)d_in[2];   // psfs [32,32,32,1,3]
    float* out = (float*)d_out;                 // pred (25165824) + loss (1)
    __bf16* psfA = (__bf16*)d_ws;               // 196608 B packed psf frags

    pack_psf<<<192, 64, 0, stream>>>(psf, psfA, out + NPRED);
    conv_mfma<<<1024, 192, 0, stream>>>(obs, img, psfA, out);
}